// Round 5
// baseline (312.168 us; speedup 1.0000x reference)
//
#include <hip/hip_runtime.h>
#include <math.h>

#define BDIM 8
#define MDIM 1024
#define CDIM 768
#define ROWS (BDIM * MDIM)   // 8192

typedef __attribute__((ext_vector_type(8))) short short8;   // 8 bf16
typedef __attribute__((ext_vector_type(8))) unsigned short ushort8;
typedef __attribute__((ext_vector_type(4))) float f32x4;

#define MFMA16(a, b, c) __builtin_amdgcn_mfma_f32_16x16x32_bf16((a), (b), (c), 0, 0, 0)

#define BAR() __builtin_amdgcn_s_barrier()
#define FENCE() asm volatile("" ::: "memory")
#define SCHED_FENCE() __builtin_amdgcn_sched_barrier(0)
#define WAIT_LGKM0() asm volatile("s_waitcnt lgkmcnt(0)" ::: "memory")
#define WAIT_VM6() asm volatile("s_waitcnt vmcnt(6)" ::: "memory")
#define WAIT_VM0() asm volatile("s_waitcnt vmcnt(0)" ::: "memory")

__device__ __forceinline__ unsigned short f2bf(float f) {
  unsigned u = __float_as_uint(f);
  return (unsigned short)((u + 0x7FFFu + ((u >> 16) & 1u)) >> 16);
}

// ---------------------------------------------------------------------------
// Prologue (one launch): input converts + weight transpose-converts.
// Flat grid of 10176 blocks x 256 threads:
//   [0,3072): convert layout_x; [3072,6144): convert text_x;
//   [6144,10176): transpose_w (168x24).
// ---------------------------------------------------------------------------
__global__ __launch_bounds__(256) void prologue(
    const float* __restrict__ xl, const float* __restrict__ xt,
    unsigned short* __restrict__ dxl, unsigned short* __restrict__ dxt,
    const float* __restrict__ W0, const float* __restrict__ W1,
    const float* __restrict__ W2, const float* __restrict__ W3,
    unsigned short* __restrict__ D0, unsigned short* __restrict__ D1,
    unsigned short* __restrict__ D2, unsigned short* __restrict__ D3) {
  const int bx = blockIdx.x;
  const int tid = threadIdx.x;
  if (bx < 6144) {
    const float* src = bx < 3072 ? xl : xt;
    unsigned short* dst = bx < 3072 ? dxl : dxt;
    const int i = ((bx < 3072 ? bx : bx - 3072) * 256 + tid) * 8;
    const float4 a = *(const float4*)(src + i);
    const float4 b = *(const float4*)(src + i + 4);
    ushort8 o;
    o[0] = f2bf(a.x); o[1] = f2bf(a.y); o[2] = f2bf(a.z); o[3] = f2bf(a.w);
    o[4] = f2bf(b.x); o[5] = f2bf(b.y); o[6] = f2bf(b.z); o[7] = f2bf(b.w);
    *(ushort8*)(dst + i) = o;
  } else {
    int x = bx - 6144;
    int bxx = x % 168;
    const int k0 = (x / 168) * 32;
    const float* W; unsigned short* D; int N;
    if (bxx < 72)       { W = W0; D = D0; N = 2304; }
    else if (bxx < 96)  { W = W1; D = D1; N = 768;  bxx -= 72; }
    else if (bxx < 144) { W = W2; D = D2; N = 1536; bxx -= 96; }
    else                { W = W3; D = D3; N = 768;  bxx -= 144; }
    __shared__ unsigned short t[32][33];
    const int tx = tid & 31, ty = tid >> 5;
    const int n0 = bxx * 32;
#pragma unroll
    for (int i = 0; i < 4; ++i)
      t[ty + i * 8][tx] = f2bf(W[(size_t)(k0 + ty + i * 8) * N + n0 + tx]);
    __syncthreads();
#pragma unroll
    for (int i = 0; i < 4; ++i)
      D[(size_t)(n0 + ty + i * 8) * CDIM + k0 + tx] = t[tx][ty + i * 8];
  }
}

// ---------------------------------------------------------------------------
// Shared staging: J row-groups of 8 rows x 64 cols per wave, XOR-chunked so
// frag reads are conflict-free (same scheme as the verified 128x128 engine).
// ---------------------------------------------------------------------------
template <int J>
__device__ __forceinline__ void stageJ(
    const unsigned short* __restrict__ g, int ld, int k0,
    unsigned short* lds, int wave, int lane) {
  const int gchunk = (lane & 7) ^ (lane >> 3);
#pragma unroll
  for (int j = 0; j < J; ++j) {
    const int grp = wave * J + j;
    const unsigned short* gp =
        g + (size_t)(grp * 8 + (lane >> 3)) * ld + k0 + gchunk * 8;
    __builtin_amdgcn_global_load_lds(
        (const __attribute__((address_space(1))) unsigned int*)gp,
        (__attribute__((address_space(3))) unsigned int*)(lds + grp * 512),
        16, 0, 0);
  }
}

// ---------------------------------------------------------------------------
// 64x128-tile MFMA engine (4 waves of 32x64, acc[2][4]). A-tile 64x64 (8KB),
// B-tile 128x64 (16KB). Used by the serial-chain kernels so their grids are
// exact multiples of 256 CUs (qk 1024, pv/cq/ffn 768 blocks) at 3-4
// blocks/CU residency — the 128^2 versions ran 384-block grids (1.5
// blocks/CU: half the CUs carry double load, thin latency hiding).
// ---------------------------------------------------------------------------
__device__ __forceinline__ void mfma_loop64h(
    const unsigned short* __restrict__ A, int lda,
    const unsigned short* __restrict__ Bt, int ldb, int K,
    unsigned short* As, unsigned short* Bs, f32x4 acc[2][4],
    int wave, int lane) {
  const int wx = wave & 1, wy = wave >> 1;
  const int quad = lane >> 4, l16 = lane & 15;
  for (int k0 = 0; k0 < K; k0 += 64) {
    stageJ<2>(A, lda, k0, As, wave, lane);
    stageJ<4>(Bt, ldb, k0, Bs, wave, lane);
    __syncthreads();
#pragma unroll
    for (int h = 0; h < 2; ++h) {
      const int slot = ((((h << 2) | quad) ^ (l16 & 7))) * 8;
      short8 afr[2], bfr[4];
#pragma unroll
      for (int mt = 0; mt < 2; ++mt)
        afr[mt] = *(const short8*)&As[(wy * 32 + mt * 16 + l16) * 64 + slot];
#pragma unroll
      for (int nt = 0; nt < 4; ++nt)
        bfr[nt] = *(const short8*)&Bs[(wx * 64 + nt * 16 + l16) * 64 + slot];
#pragma unroll
      for (int mt = 0; mt < 2; ++mt)
#pragma unroll
        for (int nt = 0; nt < 4; ++nt)
          acc[mt][nt] = MFMA16(afr[mt], bfr[nt], acc[mt][nt]);
    }
    __syncthreads();
  }
}

// ---------------------------------------------------------------------------
// 256x256 engine, 4 phases per K-tile, ONE barrier per phase (bench-best
// variant: 64.3us, MfmaUtil 30). Schedule per K-tile t:
//   p0: read A0,B0(t);  stage A1(t+1)->bufn;            BAR lgkm0 MFMA(0,0)
//   p1: read B1(t);                                     BAR lgkm0 MFMA(0,1)
//   p2: read A1(t);     stage A0(t+2)->bufc;            BAR lgkm0 MFMA(1,0)
//   p3:                 stage B0,B1(t+2)->bufc; vm(6);  BAR       MFMA(1,1)
// Clobber safety: each stage targets a slot whose last read-issue is >=2
// barriers old (reader's lgkmcnt(0) precedes the intervening barrier).
// vmcnt(6) at p3 leaves only the t+2 halves in flight.
// ---------------------------------------------------------------------------
__device__ __forceinline__ void read_fragsA(
    const unsigned short* h, int roff, short8 fr[4][2], int l16, int quad) {
#pragma unroll
  for (int mf = 0; mf < 4; ++mf)
#pragma unroll
    for (int kh = 0; kh < 2; ++kh) {
      const int slot = (((kh << 2) | quad) ^ (l16 & 7)) * 8;
      fr[mf][kh] = *(const short8*)&h[(roff + mf * 16 + l16) * 64 + slot];
    }
}

__device__ __forceinline__ void read_fragsB(
    const unsigned short* h, int roff, short8 fr[2][2], int l16, int quad) {
#pragma unroll
  for (int nf = 0; nf < 2; ++nf)
#pragma unroll
    for (int kh = 0; kh < 2; ++kh) {
      const int slot = (((kh << 2) | quad) ^ (l16 & 7)) * 8;
      fr[nf][kh] = *(const short8*)&h[(roff + nf * 16 + l16) * 64 + slot];
    }
}

#define MFMA_PHASE(GM, GN, BB)                                              \
  do {                                                                      \
    SCHED_FENCE();                                                          \
    __builtin_amdgcn_s_setprio(1);                                          \
    _Pragma("unroll") for (int mf = 0; mf < 4; ++mf)                        \
    _Pragma("unroll") for (int nf = 0; nf < 2; ++nf)                        \
    _Pragma("unroll") for (int kh = 0; kh < 2; ++kh)                        \
        acc[GM][GN][mf][nf] =                                               \
            MFMA16(afr[mf][kh], BB[nf][kh], acc[GM][GN][mf][nf]);           \
    __builtin_amdgcn_s_setprio(0);                                          \
    SCHED_FENCE();                                                          \
  } while (0)

// Combined qkv (layout_x@Wqkv, 288 blocks) + kv (text_x@Wkv, 192 blocks):
// both K=768, equal-cost blocks, 480 total = 94%-balanced 2 rounds.
// Last 768-slice of each is written transposed into vTd[b][d][n].
__global__ __launch_bounds__(512, 2) void gemm_qkvkv(
    const unsigned short* __restrict__ A0g, const unsigned short* __restrict__ B0g,
    const float* __restrict__ bias0, unsigned short* __restrict__ Y0,
    unsigned short* __restrict__ vT0,
    const unsigned short* __restrict__ A1g, const unsigned short* __restrict__ B1g,
    const float* __restrict__ bias1, unsigned short* __restrict__ Y1,
    unsigned short* __restrict__ vT1) {
  __shared__ __align__(16) unsigned short lds[65536];  // 128 KiB
  int lin = blockIdx.x;
  const unsigned short *A, *Bt; const float* bias;
  unsigned short *Y, *vTd; int lastSlice, m0, c0;
  if (lin < 288) {            // qkv: 32 m-tiles x 9 c-tiles
    A = A0g; Bt = B0g; bias = bias0; Y = Y0; vTd = vT0; lastSlice = 2;
    const int xcd = lin & 7, j = lin >> 3;          // j in [0,36)
    m0 = (xcd * 4 + (j & 3)) * 256; c0 = (j >> 2) * 256;
  } else {                    // kv: 32 m-tiles x 6 c-tiles
    lin -= 288;
    A = A1g; Bt = B1g; bias = bias1; Y = Y1; vTd = vT1; lastSlice = 1;
    const int xcd = lin & 7, j = lin >> 3;          // j in [0,24)
    m0 = (xcd * 4 + (j & 3)) * 256; c0 = (j >> 2) * 256;
  }
  const int tid = threadIdx.x;
  const int wave = tid >> 6, lane = tid & 63;
  const int wy = wave >> 2, wx = wave & 3;          // 2 x 4 waves
  const int quad = lane >> 4, l16 = lane & 15;

  const unsigned short* Ah[2] = {A + (size_t)m0 * CDIM,
                                 A + (size_t)(m0 + 128) * CDIM};
  const unsigned short* Bh[2] = {Bt + (size_t)c0 * CDIM,
                                 Bt + (size_t)(c0 + 128) * CDIM};

  const f32x4 vzero = {0.f, 0.f, 0.f, 0.f};
  f32x4 acc[2][2][4][2];
#pragma unroll
  for (int gm = 0; gm < 2; ++gm)
#pragma unroll
    for (int gn = 0; gn < 2; ++gn)
#pragma unroll
      for (int mf = 0; mf < 4; ++mf)
#pragma unroll
        for (int nf = 0; nf < 2; ++nf) acc[gm][gn][mf][nf] = vzero;
  short8 afr[4][2], b0r[2][2], b1r[2][2];

  // Prologue staging: kt0 {A0,B0,B1,A1} + kt1 {A0,B0,B1} (A1(1) is staged at
  // p0 of t=0). Wait kt0 landed (6 of kt1 left in flight).
  stageJ<2>(Ah[0], CDIM, 0, lds + 0, wave, lane);
  stageJ<2>(Bh[0], CDIM, 0, lds + 16384, wave, lane);
  stageJ<2>(Bh[1], CDIM, 0, lds + 24576, wave, lane);
  stageJ<2>(Ah[1], CDIM, 0, lds + 8192, wave, lane);
  stageJ<2>(Ah[0], CDIM, 64, lds + 32768 + 0, wave, lane);
  stageJ<2>(Bh[0], CDIM, 64, lds + 32768 + 16384, wave, lane);
  stageJ<2>(Bh[1], CDIM, 64, lds + 32768 + 24576, wave, lane);
  WAIT_VM6();
  BAR(); FENCE();

  for (int t = 0; t < 12; ++t) {
    unsigned short* bufc = lds + (t & 1) * 32768;
    unsigned short* bufn = lds + ((t + 1) & 1) * 32768;
    // ---- phase 0: quadrant (0,0) ----
    read_fragsA(bufc + 0, wy * 64, afr, l16, quad);
    read_fragsB(bufc + 16384, wx * 32, b0r, l16, quad);
    if (t < 11) stageJ<2>(Ah[1], CDIM, (t + 1) * 64, bufn + 8192, wave, lane);
    BAR(); WAIT_LGKM0();
    MFMA_PHASE(0, 0, b0r);
    // ---- phase 1: quadrant (0,1) ----
    read_fragsB(bufc + 24576, wx * 32, b1r, l16, quad);
    BAR(); WAIT_LGKM0();
    MFMA_PHASE(0, 1, b1r);
    // ---- phase 2: quadrant (1,0) ----
    read_fragsA(bufc + 8192, wy * 64, afr, l16, quad);
    if (t < 10) stageJ<2>(Ah[0], CDIM, (t + 2) * 64, bufc + 0, wave, lane);
    BAR(); WAIT_LGKM0();
    MFMA_PHASE(1, 0, b0r);
    // ---- phase 3: quadrant (1,1) + K-tile boundary ----
    if (t < 10) {
      stageJ<2>(Bh[0], CDIM, (t + 2) * 64, bufc + 16384, wave, lane);
      stageJ<2>(Bh[1], CDIM, (t + 2) * 64, bufc + 24576, wave, lane);
      WAIT_VM6();
    } else if (t == 10) {
      WAIT_VM0();
    }
    BAR(); FENCE();
    MFMA_PHASE(1, 1, b1r);
  }

  // Epilogue: slice-routed writes (last slice transposed to vTd[b][d][n]).
#pragma unroll
  for (int gm = 0; gm < 2; ++gm)
#pragma unroll
    for (int gn = 0; gn < 2; ++gn) {
      const int cb2 = c0 + gn * 128 + wx * 32;
      const int slice = cb2 / 768;
      const int rb = m0 + gm * 128 + wy * 64;
      if (slice == lastSlice) {
#pragma unroll
        for (int mf = 0; mf < 4; ++mf) {
          const int row0 = rb + mf * 16 + quad * 4;
          const int b = row0 >> 10, n0 = row0 & 1023;
#pragma unroll
          for (int nf = 0; nf < 2; ++nf) {
            const int gcol = cb2 + nf * 16 + l16;
            const int d = gcol - slice * 768;
            const float bv = bias[gcol];
            uint2 o;
            o.x = (unsigned)f2bf(acc[gm][gn][mf][nf][0] + bv) |
                  ((unsigned)f2bf(acc[gm][gn][mf][nf][1] + bv) << 16);
            o.y = (unsigned)f2bf(acc[gm][gn][mf][nf][2] + bv) |
                  ((unsigned)f2bf(acc[gm][gn][mf][nf][3] + bv) << 16);
            *(uint2*)&vTd[((size_t)b * CDIM + d) * MDIM + n0] = o;
          }
        }
      } else {
        const size_t sbase = (size_t)slice * ROWS * 768;
#pragma unroll
        for (int mf = 0; mf < 4; ++mf)
#pragma unroll
          for (int nf = 0; nf < 2; ++nf) {
            const int gcol = cb2 + nf * 16 + l16;
            const int lcol = gcol - slice * 768;
            const float bv = bias[gcol];
#pragma unroll
            for (int rg = 0; rg < 4; ++rg) {
              const int row = rb + mf * 16 + quad * 4 + rg;
              Y[sbase + (size_t)row * 768 + lcol] =
                  f2bf(acc[gm][gn][mf][nf][rg] + bv);
            }
          }
      }
    }
}

// ---------------------------------------------------------------------------
// cq projection on the 64x128 engine: flat grid 768 (=3.0 blocks/CU),
// m0 = 64-row tiles, XCD-chunked.
// ---------------------------------------------------------------------------
__global__ __launch_bounds__(256, 4) void gemm_proj64(
    const unsigned short* __restrict__ A, const unsigned short* __restrict__ Bt,
    const float* __restrict__ bias, unsigned short* __restrict__ Y) {
  __shared__ __align__(16) unsigned short As[64 * 64];
  __shared__ __align__(16) unsigned short Bs[128 * 64];
  const int lin = blockIdx.x;
  const int xcd = lin & 7, j = lin >> 3;            // j in [0,96)
  const int m0 = (xcd * 16 + (j & 15)) * 64;
  const int c0 = (j >> 4) * 128;
  const int tid = threadIdx.x;
  const int wave = tid >> 6, lane = tid & 63;
  const int wx = wave & 1, wy = wave >> 1;
  const int quad = lane >> 4, l16 = lane & 15;
  const f32x4 vzero = {0.f, 0.f, 0.f, 0.f};
  f32x4 acc[2][4];
#pragma unroll
  for (int mt = 0; mt < 2; ++mt)
#pragma unroll
    for (int nt = 0; nt < 4; ++nt) acc[mt][nt] = vzero;
  mfma_loop64h(A + (size_t)m0 * CDIM, CDIM, Bt + (size_t)c0 * CDIM, CDIM,
               CDIM, As, Bs, acc, wave, lane);
#pragma unroll
  for (int mt = 0; mt < 2; ++mt)
#pragma unroll
    for (int nt = 0; nt < 4; ++nt) {
      const int col = c0 + wx * 64 + nt * 16 + l16;
      const float bv = bias[col];
#pragma unroll
      for (int rg = 0; rg < 4; ++rg) {
        const int row = m0 + wy * 32 + mt * 16 + quad * 4 + rg;
        Y[(size_t)row * 768 + col] = f2bf(acc[mt][nt][rg] + bv);
      }
    }
}

// FFN on the 64x128 engine (f32 out): flat grid 768.
__global__ __launch_bounds__(256, 4) void gemm_ffn64(
    const unsigned short* __restrict__ A, const unsigned short* __restrict__ Bt,
    const float* __restrict__ bias, float* __restrict__ Y) {
  __shared__ __align__(16) unsigned short As[64 * 64];
  __shared__ __align__(16) unsigned short Bs[128 * 64];
  const int lin = blockIdx.x;
  const int xcd = lin & 7, j = lin >> 3;
  const int m0 = (xcd * 16 + (j & 15)) * 64;
  const int c0 = (j >> 4) * 128;
  const int tid = threadIdx.x;
  const int wave = tid >> 6, lane = tid & 63;
  const int wx = wave & 1, wy = wave >> 1;
  const int quad = lane >> 4, l16 = lane & 15;
  const f32x4 vzero = {0.f, 0.f, 0.f, 0.f};
  f32x4 acc[2][4];
#pragma unroll
  for (int mt = 0; mt < 2; ++mt)
#pragma unroll
    for (int nt = 0; nt < 4; ++nt) acc[mt][nt] = vzero;
  mfma_loop64h(A + (size_t)m0 * CDIM, CDIM, Bt + (size_t)c0 * CDIM, CDIM,
               CDIM, As, Bs, acc, wave, lane);
#pragma unroll
  for (int mt = 0; mt < 2; ++mt)
#pragma unroll
    for (int nt = 0; nt < 4; ++nt) {
      const int col = c0 + wx * 64 + nt * 16 + l16;
      const float bv = bias[col];
#pragma unroll
      for (int rg = 0; rg < 4; ++rg) {
        const int row = m0 + wy * 32 + mt * 16 + quad * 4 + rg;
        Y[(size_t)row * 768 + col] = acc[mt][nt][rg] + bv;
      }
    }
}

// ---------------------------------------------------------------------------
// Batched QK^T with fused exp + row-sum on the 64x128 engine.
// grid (8, 16, BDIM) = 1024 blocks = 4.0 blocks/CU. Row sums stored as
// race-free partials per (cblock, wx): rsp[((cb*2+wx)*8 + b)*1024 + row]
// (16 partials per row, no atomics, no zero-init).
// ---------------------------------------------------------------------------
__global__ __launch_bounds__(256, 4) void gemm_qk64(
    const unsigned short* __restrict__ Qb, const unsigned short* __restrict__ Kb,
    const float* __restrict__ mask, unsigned short* __restrict__ S, float scale,
    float* __restrict__ rsp) {
  __shared__ __align__(16) unsigned short As[64 * 64];
  __shared__ __align__(16) unsigned short Bs[128 * 64];
  const int c0 = blockIdx.x * 128;
  const int m0 = blockIdx.y * 64;
  const int b = blockIdx.z;
  const int tid = threadIdx.x;
  const int wave = tid >> 6, lane = tid & 63;
  const int wx = wave & 1, wy = wave >> 1;
  const int quad = lane >> 4, l16 = lane & 15;

  const f32x4 vzero = {0.f, 0.f, 0.f, 0.f};
  f32x4 acc[2][4];
#pragma unroll
  for (int mt = 0; mt < 2; ++mt)
#pragma unroll
    for (int nt = 0; nt < 4; ++nt) acc[mt][nt] = vzero;

  mfma_loop64h(Qb + ((size_t)b * MDIM + m0) * CDIM, CDIM,
               Kb + ((size_t)b * MDIM + c0) * CDIM, CDIM, CDIM,
               As, Bs, acc, wave, lane);

  const float* maskb = mask + b * MDIM;
  float mrow[2][4], rsum[2][4];
#pragma unroll
  for (int mt = 0; mt < 2; ++mt)
#pragma unroll
    for (int rg = 0; rg < 4; ++rg) {
      mrow[mt][rg] = maskb[m0 + wy * 32 + mt * 16 + quad * 4 + rg];
      rsum[mt][rg] = 0.f;
    }
  unsigned short* Sb = S + (size_t)b * MDIM * MDIM;
#pragma unroll
  for (int nt = 0; nt < 4; ++nt) {
    const int col = c0 + wx * 64 + nt * 16 + l16;
    const float mcol = maskb[col];
#pragma unroll
    for (int mt = 0; mt < 2; ++mt)
#pragma unroll
      for (int rg = 0; rg < 4; ++rg) {
        const int row = m0 + wy * 32 + mt * 16 + quad * 4 + rg;
        const float e = (mrow[mt][rg] * mcol != 0.f)
                            ? __expf(acc[mt][nt][rg] * scale)
                            : 1e-30f;
        Sb[(size_t)row * MDIM + col] = f2bf(e);
        rsum[mt][rg] += e;
      }
  }
  // reduce across the 16 lanes of each quad (they share rows)
  for (int off = 1; off < 16; off <<= 1) {
#pragma unroll
    for (int mt = 0; mt < 2; ++mt)
#pragma unroll
      for (int rg = 0; rg < 4; ++rg)
        rsum[mt][rg] += __shfl_xor(rsum[mt][rg], off, 64);
  }
  if (l16 == 0) {
    float* rs = rsp + ((((size_t)blockIdx.x * 2 + wx) * 8 + b) << 10) +
                m0 + wy * 32;
#pragma unroll
    for (int mt = 0; mt < 2; ++mt)
#pragma unroll
      for (int rg = 0; rg < 4; ++rg)
        rs[mt * 16 + quad * 4 + rg] = rsum[mt][rg];
  }
}

// ---------------------------------------------------------------------------
// O = (unnormalized P) @ V, normalized by 1/rowsum, on the 64x128 engine.
// grid (6, 16, BDIM) = 768 blocks = 3.0 blocks/CU. rowsum = sum of 16
// partials (lane l16 loads partial l16, 16-lane shuffle reduce).
// ---------------------------------------------------------------------------
__global__ __launch_bounds__(256, 4) void attn_pv64(
    const unsigned short* __restrict__ P, const unsigned short* __restrict__ vT,
    unsigned short* __restrict__ O, const float* __restrict__ rsp) {
  __shared__ __align__(16) unsigned short As[64 * 64];
  __shared__ __align__(16) unsigned short Bs[128 * 64];
  const int c0 = blockIdx.x * 128;
  const int m0 = blockIdx.y * 64;
  const int b = blockIdx.z;
  const int tid = threadIdx.x;
  const int wave = tid >> 6, lane = tid & 63;
  const int wx = wave & 1, wy = wave >> 1;
  const int quad = lane >> 4, l16 = lane & 15;

  const f32x4 vzero = {0.f, 0.f, 0.f, 0.f};
  f32x4 acc[2][4];
#pragma unroll
  for (int mt = 0; mt < 2; ++mt)
#pragma unroll
    for (int nt = 0; nt < 4; ++nt) acc[mt][nt] = vzero;

  mfma_loop64h(P + ((size_t)b * MDIM + m0) * MDIM, MDIM,
               vT + ((size_t)b * CDIM + c0) * MDIM, MDIM, MDIM,
               As, Bs, acc, wave, lane);

  const float* rsb = rsp + (((size_t)l16 * 8 + b) << 10) + m0 + wy * 32;
  float inv[2][4];
#pragma unroll
  for (int mt = 0; mt < 2; ++mt)
#pragma unroll
    for (int rg = 0; rg < 4; ++rg) {
      float s = rsb[mt * 16 + quad * 4 + rg];
      for (int off = 1; off < 16; off <<= 1) s += __shfl_xor(s, off, 64);
      inv[mt][rg] = 1.f / s;
    }
#pragma unroll
  for (int mt = 0; mt < 2; ++mt)
#pragma unroll
    for (int nt = 0; nt < 4; ++nt)
#pragma unroll
      for (int rg = 0; rg < 4; ++rg) {
        const int row = m0 + wy * 32 + mt * 16 + quad * 4 + rg;
        const int col = c0 + wx * 64 + nt * 16 + l16;
        O[(size_t)(b * MDIM + row) * CDIM + col] =
            f2bf(acc[mt][nt][rg] * inv[mt][rg]);
      }
}

// ---------------------------------------------------------------------------
extern "C" void kernel_launch(void* const* d_in, const int* in_sizes, int n_in,
                              void* d_out, int out_size, void* d_ws, size_t ws_size,
                              hipStream_t stream) {
  const float* layout_x = (const float*)d_in[0];
  const float* text_x   = (const float*)d_in[1];
  const float* maskp    = (const float*)d_in[2];
  const float* Wqkv     = (const float*)d_in[3];
  const float* bqkv     = (const float*)d_in[4];
  const float* Wq       = (const float*)d_in[5];
  const float* bq       = (const float*)d_in[6];
  const float* Wkv      = (const float*)d_in[7];
  const float* bkv      = (const float*)d_in[8];
  const float* Wffn     = (const float*)d_in[9];
  const float* bffn     = (const float*)d_in[10];
  float* out = (float*)d_out;
  char* ws = (char*)d_ws;

  const float scale = 1.0f / sqrtf((float)CDIM);

  // ---- workspace (bytes), live total 87,949,312 ----
  unsigned short* xlb    = (unsigned short*)(ws);              // -> attn1/merge
  unsigned short* xtb    = (unsigned short*)(ws + 12582912);   // dead after proj -> rsp
  unsigned short* Wqkv_t = (unsigned short*)(ws + 25165824);
  unsigned short* Wq_t   = (unsigned short*)(ws + 28704768);
  unsigned short* Wkv_t  = (unsigned short*)(ws + 29884416);
  unsigned short* Wffn_t = (unsigned short*)(ws + 32243712);
  unsigned short* Qb     = (unsigned short*)(ws + 33423360);   // slice1=K contiguous
  unsigned short* Kb     = (unsigned short*)(ws + 46006272);
  unsigned short* vT     = (unsigned short*)(ws + 58589184);   // V^T
  unsigned short* S      = (unsigned short*)(ws + 71172096);   // 16.8 MB
  unsigned short* attn1  = xlb;
  unsigned short* cqb    = Qb;           // Qb dead after qk1
  // cross-attention K / V^T live in d_out (exactly 2 x 12,582,912 B);
  // ffn overwrites out only after pv2 consumed them.
  unsigned short* cK  = (unsigned short*)out;
  unsigned short* cVT = (unsigned short*)out + 6291456;
  // rowsum partials (512 KB) in the xtb region (dead after gemm_qkvkv).
  float* rsp = (float*)xtb;

  // 1) prologue: input converts + weight transposes
  prologue<<<10176, 256, 0, stream>>>(layout_x, text_x, xlb, xtb,
                                      Wqkv, Wq, Wkv, Wffn,
                                      Wqkv_t, Wq_t, Wkv_t, Wffn_t);
  // 2) combined 256^2 engine: {Q,K -> Qb,Kb; V -> vT^T} + {cK -> out; cV -> cVT^T}
  gemm_qkvkv<<<480, 512, 0, stream>>>(xlb, Wqkv_t, bqkv, Qb, vT,
                                      xtb, Wkv_t, bkv, cK, cVT);
  // 3) S = exp(scale*QK^T) masked; rowsum partials
  gemm_qk64<<<dim3(8, 16, BDIM), 256, 0, stream>>>(Qb, Kb, maskp, S, scale, rsp);
  // 4) attn1 = bf16((S @ V) / rowsum)
  attn_pv64<<<dim3(6, 16, BDIM), 256, 0, stream>>>(S, vT, attn1, rsp);
  // 5) cq = attn1@Wq+bq
  gemm_proj64<<<768, 256, 0, stream>>>(attn1, Wq_t, bq, cqb);
  // 6) S = exp(scale*cq cK^T) masked; rowsum partials
  gemm_qk64<<<dim3(8, 16, BDIM), 256, 0, stream>>>(cqb, cK, maskp, S, scale, rsp);
  // 7) merge = bf16((S @ cV) / rowsum)
  attn_pv64<<<dim3(6, 16, BDIM), 256, 0, stream>>>(S, cVT, attn1, rsp);
  // 8) out = merge @ Wffn + bffn (f32)
  gemm_ffn64<<<768, 256, 0, stream>>>(attn1, Wffn_t, bffn, out);
}

// Round 7
// 306.106 us; speedup vs baseline: 1.0198x; 1.0198x over previous
//
#include <hip/hip_runtime.h>
#include <math.h>

#define BDIM 8
#define MDIM 1024
#define CDIM 768
#define ROWS (BDIM * MDIM)   // 8192

typedef __attribute__((ext_vector_type(8))) short short8;   // 8 bf16
typedef __attribute__((ext_vector_type(8))) unsigned short ushort8;
typedef __attribute__((ext_vector_type(4))) float f32x4;

#define MFMA16(a, b, c) __builtin_amdgcn_mfma_f32_16x16x32_bf16((a), (b), (c), 0, 0, 0)

#define BAR() __builtin_amdgcn_s_barrier()
#define FENCE() asm volatile("" ::: "memory")
#define SCHED_FENCE() __builtin_amdgcn_sched_barrier(0)
#define WAIT_LGKM0() asm volatile("s_waitcnt lgkmcnt(0)" ::: "memory")
#define WAIT_LGKM4() asm volatile("s_waitcnt lgkmcnt(4)" ::: "memory")
#define WAIT_LGKM8() asm volatile("s_waitcnt lgkmcnt(8)" ::: "memory")
#define WAIT_VM8() asm volatile("s_waitcnt vmcnt(8)" ::: "memory")
#define WAIT_VM6() asm volatile("s_waitcnt vmcnt(6)" ::: "memory")
#define WAIT_VM4() asm volatile("s_waitcnt vmcnt(4)" ::: "memory")
#define WAIT_VM2() asm volatile("s_waitcnt vmcnt(2)" ::: "memory")
#define WAIT_VM0() asm volatile("s_waitcnt vmcnt(0)" ::: "memory")

__device__ __forceinline__ unsigned short f2bf(float f) {
  unsigned u = __float_as_uint(f);
  return (unsigned short)((u + 0x7FFFu + ((u >> 16) & 1u)) >> 16);
}

// Inline-asm ds_read_b128: the counted lgkm waits only bind to reads emitted
// as asm; C++ ds_reads get sunk past the asm waitcnt and the compiler then
// inserts its own FULL s_waitcnt before the MFMA cluster (rule #18 inverse),
// which silently re-serializes every schedule variant to read->drain->MFMA
// (measured 25-30% MfmaUtil across R1-R5).
__device__ __forceinline__ short8 dsr128(unsigned off) {
  short8 r;
  asm volatile("ds_read_b128 %0, %1" : "=v"(r) : "v"(off));
  return r;
}

// ---------------------------------------------------------------------------
// Prologue (one launch): input converts + weight transpose-converts.
// Flat grid of 10176 blocks x 256 threads:
//   [0,3072): convert layout_x; [3072,6144): convert text_x;
//   [6144,10176): transpose_w (168x24).
// ---------------------------------------------------------------------------
__global__ __launch_bounds__(256) void prologue(
    const float* __restrict__ xl, const float* __restrict__ xt,
    unsigned short* __restrict__ dxl, unsigned short* __restrict__ dxt,
    const float* __restrict__ W0, const float* __restrict__ W1,
    const float* __restrict__ W2, const float* __restrict__ W3,
    unsigned short* __restrict__ D0, unsigned short* __restrict__ D1,
    unsigned short* __restrict__ D2, unsigned short* __restrict__ D3) {
  const int bx = blockIdx.x;
  const int tid = threadIdx.x;
  if (bx < 6144) {
    const float* src = bx < 3072 ? xl : xt;
    unsigned short* dst = bx < 3072 ? dxl : dxt;
    const int i = ((bx < 3072 ? bx : bx - 3072) * 256 + tid) * 8;
    const float4 a = *(const float4*)(src + i);
    const float4 b = *(const float4*)(src + i + 4);
    ushort8 o;
    o[0] = f2bf(a.x); o[1] = f2bf(a.y); o[2] = f2bf(a.z); o[3] = f2bf(a.w);
    o[4] = f2bf(b.x); o[5] = f2bf(b.y); o[6] = f2bf(b.z); o[7] = f2bf(b.w);
    *(ushort8*)(dst + i) = o;
  } else {
    int x = bx - 6144;
    int bxx = x % 168;
    const int k0 = (x / 168) * 32;
    const float* W; unsigned short* D; int N;
    if (bxx < 72)       { W = W0; D = D0; N = 2304; }
    else if (bxx < 96)  { W = W1; D = D1; N = 768;  bxx -= 72; }
    else if (bxx < 144) { W = W2; D = D2; N = 1536; bxx -= 96; }
    else                { W = W3; D = D3; N = 768;  bxx -= 144; }
    __shared__ unsigned short t[32][33];
    const int tx = tid & 31, ty = tid >> 5;
    const int n0 = bxx * 32;
#pragma unroll
    for (int i = 0; i < 4; ++i)
      t[ty + i * 8][tx] = f2bf(W[(size_t)(k0 + ty + i * 8) * N + n0 + tx]);
    __syncthreads();
#pragma unroll
    for (int i = 0; i < 4; ++i)
      D[(size_t)(n0 + ty + i * 8) * CDIM + k0 + tx] = t[tx][ty + i * 8];
  }
}

// ---------------------------------------------------------------------------
// Shared staging: J row-groups of 8 rows x 64 cols per wave, XOR-chunked so
// frag reads are conflict-free (same scheme as the verified 128x128 engine).
// ---------------------------------------------------------------------------
template <int J>
__device__ __forceinline__ void stageJ(
    const unsigned short* __restrict__ g, int ld, int k0,
    unsigned short* lds, int wave, int lane) {
  const int gchunk = (lane & 7) ^ (lane >> 3);
#pragma unroll
  for (int j = 0; j < J; ++j) {
    const int grp = wave * J + j;
    const unsigned short* gp =
        g + (size_t)(grp * 8 + (lane >> 3)) * ld + k0 + gchunk * 8;
    __builtin_amdgcn_global_load_lds(
        (const __attribute__((address_space(1))) unsigned int*)gp,
        (__attribute__((address_space(3))) unsigned int*)(lds + grp * 512),
        16, 0, 0);
  }
}

// ---------------------------------------------------------------------------
// 64x128-tile MFMA engine (4 waves of 32x64, acc[2][4]). A-tile 64x64 (8KB),
// B-tile 128x64 (16KB). Chain kernels: grids exact multiples of 256 CUs
// (qk 1024, pv/cq/ffn 768 blocks) at 3-4 blocks/CU residency.
// ---------------------------------------------------------------------------
__device__ __forceinline__ void mfma_loop64h(
    const unsigned short* __restrict__ A, int lda,
    const unsigned short* __restrict__ Bt, int ldb, int K,
    unsigned short* As, unsigned short* Bs, f32x4 acc[2][4],
    int wave, int lane) {
  const int wx = wave & 1, wy = wave >> 1;
  const int quad = lane >> 4, l16 = lane & 15;
  for (int k0 = 0; k0 < K; k0 += 64) {
    stageJ<2>(A, lda, k0, As, wave, lane);
    stageJ<4>(Bt, ldb, k0, Bs, wave, lane);
    __syncthreads();
#pragma unroll
    for (int h = 0; h < 2; ++h) {
      const int slot = ((((h << 2) | quad) ^ (l16 & 7))) * 8;
      short8 afr[2], bfr[4];
#pragma unroll
      for (int mt = 0; mt < 2; ++mt)
        afr[mt] = *(const short8*)&As[(wy * 32 + mt * 16 + l16) * 64 + slot];
#pragma unroll
      for (int nt = 0; nt < 4; ++nt)
        bfr[nt] = *(const short8*)&Bs[(wx * 64 + nt * 16 + l16) * 64 + slot];
#pragma unroll
      for (int mt = 0; mt < 2; ++mt)
#pragma unroll
        for (int nt = 0; nt < 4; ++nt)
          acc[mt][nt] = MFMA16(afr[mt], bfr[nt], acc[mt][nt]);
    }
    __syncthreads();
  }
}

#define MFMA_PHASE(GM, GN, AA, BB)                                          \
  do {                                                                      \
    SCHED_FENCE();                                                          \
    __builtin_amdgcn_s_setprio(1);                                          \
    _Pragma("unroll") for (int mf = 0; mf < 4; ++mf)                        \
    _Pragma("unroll") for (int nf = 0; nf < 2; ++nf)                        \
    _Pragma("unroll") for (int kh = 0; kh < 2; ++kh)                        \
        acc[GM][GN][mf][nf] =                                               \
            MFMA16(AA[mf][kh], BB[nf][kh], acc[GM][GN][mf][nf]);            \
    __builtin_amdgcn_s_setprio(0);                                          \
    SCHED_FENCE();                                                          \
  } while (0)

// asm frag reads: byte offsets into the (sole) LDS allocation (addr 0).
#define RD_A(dst, base)                                                     \
  do {                                                                      \
    _Pragma("unroll") for (int mf = 0; mf < 4; ++mf) {                      \
      dst[mf][0] = dsr128((base) + aRow[mf] + sl0);                         \
      dst[mf][1] = dsr128((base) + aRow[mf] + sl1);                         \
    }                                                                       \
  } while (0)
#define RD_B(dst, base)                                                     \
  do {                                                                      \
    _Pragma("unroll") for (int nf = 0; nf < 2; ++nf) {                      \
      dst[nf][0] = dsr128((base) + bRow[nf] + sl0);                         \
      dst[nf][1] = dsr128((base) + bRow[nf] + sl1);                         \
    }                                                                       \
  } while (0)

// ---------------------------------------------------------------------------
// 256x256 engine, register-pipelined with ASM ds_reads + counted waits.
// 512 threads = 8 waves (2M x 4N); per-wave output 128x64; BK=64; 12 K-tiles.
// LDS 128 KiB: 2 dbuf x {A0,A1,B0,B1} halves of [128][64] bf16, chunk-XOR
// swizzled. Byte sections: A0=0, A1=16384, B0=32768, B1=49152; buf +65536.
//
// Steady phase p of K-tile t (bc=byte base of buf[t&1], bn=buf[(t+1)&1]):
//   P0: rdB b1r<-B1(t)@bc;  st A1(t+1)->bn; vm8 BAR lgkm4; MFMA(0,0)[afrE,b0r]
//   P1: rdA afrO<-A1(t)@bc; st A0(t+2)->bc; vm8 BAR lgkm8; MFMA(0,1)[afrE,b1r]
//   P2: rdA afrE<-A0(t+1)@bn; st B0(t+2)->bc; vm8 BAR lgkm8; MFMA(1,0)[afrO,b0r]
//   P3: rdB b0r<-B0(t+1)@bn;  st B1(t+2)->bc; vm8 BAR;      MFMA(1,1)[afrO,b1r]
//
// lgkm ledger (outstanding -> after wait): P0: 16->4 (drains afrE,b0r for
// (0,0)); P1: 12->8 (drains b1r for (0,1)); P2: 16->8 (drains afrO for
// (1,0)); P3: none needed ((1,1) operands drained at P1/P2). Register sets
// per phase are disjoint from the in-flight reads -> no WAR hazards.
// vm8: 4 halves (8 loads/thread) stay in flight; the half read next phase is
// always older than the newest 8 (verified by issue-order ledger), and the
// barrier publishes all waves' waits. Clobber safety: every staged slot's
// last read-issue is >=3 barriers old. Tails: vm decay 8/6/4/2/0.
// ---------------------------------------------------------------------------
__global__ __launch_bounds__(512, 2) void gemm_qkvkv(
    const unsigned short* __restrict__ A0g, const unsigned short* __restrict__ B0g,
    const float* __restrict__ bias0, unsigned short* __restrict__ Y0,
    unsigned short* __restrict__ vT0,
    const unsigned short* __restrict__ A1g, const unsigned short* __restrict__ B1g,
    const float* __restrict__ bias1, unsigned short* __restrict__ Y1,
    unsigned short* __restrict__ vT1) {
  __shared__ __align__(16) unsigned short lds[65536];  // 128 KiB, LDS addr 0
  int lin = blockIdx.x;
  const unsigned short *A, *Bt; const float* bias;
  unsigned short *Y, *vTd; int lastSlice, m0, c0;
  if (lin < 288) {            // qkv: 32 m-tiles x 9 c-tiles
    A = A0g; Bt = B0g; bias = bias0; Y = Y0; vTd = vT0; lastSlice = 2;
    const int xcd = lin & 7, j = lin >> 3;          // j in [0,36)
    m0 = (xcd * 4 + (j & 3)) * 256; c0 = (j >> 2) * 256;
  } else {                    // kv: 32 m-tiles x 6 c-tiles
    lin -= 288;
    A = A1g; Bt = B1g; bias = bias1; Y = Y1; vTd = vT1; lastSlice = 1;
    const int xcd = lin & 7, j = lin >> 3;          // j in [0,24)
    m0 = (xcd * 4 + (j & 3)) * 256; c0 = (j >> 2) * 256;
  }
  const int tid = threadIdx.x;
  const int wave = tid >> 6, lane = tid & 63;
  const int wy = wave >> 2, wx = wave & 3;          // 2 x 4 waves
  const int quad = lane >> 4, l16 = lane & 15;

  const unsigned short* Ah[2] = {A + (size_t)m0 * CDIM,
                                 A + (size_t)(m0 + 128) * CDIM};
  const unsigned short* Bh[2] = {Bt + (size_t)c0 * CDIM,
                                 Bt + (size_t)(c0 + 128) * CDIM};

  // LDS byte-offset bases for asm reads.
  const unsigned sl0 = (unsigned)((quad ^ (l16 & 7)) * 16);
  const unsigned sl1 = (unsigned)(((4 | quad) ^ (l16 & 7)) * 16);
  unsigned aRow[4], bRow[2];
#pragma unroll
  for (int mf = 0; mf < 4; ++mf)
    aRow[mf] = (unsigned)((wy * 64 + mf * 16 + l16) * 128);
#pragma unroll
  for (int nf = 0; nf < 2; ++nf)
    bRow[nf] = (unsigned)((wx * 32 + nf * 16 + l16) * 128);

  const f32x4 vzero = {0.f, 0.f, 0.f, 0.f};
  f32x4 acc[2][2][4][2];
#pragma unroll
  for (int gm = 0; gm < 2; ++gm)
#pragma unroll
    for (int gn = 0; gn < 2; ++gn)
#pragma unroll
      for (int mf = 0; mf < 4; ++mf)
#pragma unroll
        for (int nf = 0; nf < 2; ++nf) acc[gm][gn][mf][nf] = vzero;
  short8 afrE[4][2], afrO[4][2], b0r[2][2], b1r[2][2];

  // Prologue: stage buf0{A0,B0,B1,A1}(t0) + buf1{A0,B0,B1}(t1) = 14 loads;
  // vm8 lands the 6 oldest (A0,B0,B1 of t0); BAR; issue the t0 P0 operand
  // reads (drained by the first P0's lgkm4).
  stageJ<2>(Ah[0], CDIM, 0, lds + 0, wave, lane);
  stageJ<2>(Bh[0], CDIM, 0, lds + 16384, wave, lane);
  stageJ<2>(Bh[1], CDIM, 0, lds + 24576, wave, lane);
  stageJ<2>(Ah[1], CDIM, 0, lds + 8192, wave, lane);
  stageJ<2>(Ah[0], CDIM, 64, lds + 32768 + 0, wave, lane);
  stageJ<2>(Bh[0], CDIM, 64, lds + 32768 + 16384, wave, lane);
  stageJ<2>(Bh[1], CDIM, 64, lds + 32768 + 24576, wave, lane);
  WAIT_VM8();
  BAR(); FENCE();
  RD_A(afrE, 0u);        // A0(0) @ buf0
  RD_B(b0r, 32768u);     // B0(0) @ buf0

  for (int t = 0; t < 10; ++t) {
    unsigned short* bufcP = lds + (t & 1) * 32768;
    unsigned short* bufnP = lds + ((t + 1) & 1) * 32768;
    const unsigned bc = (unsigned)((t & 1) * 65536);
    const unsigned bn = (unsigned)(((t + 1) & 1) * 65536);
    // ---- P0 ----
    RD_B(b1r, bc + 49152u);
    stageJ<2>(Ah[1], CDIM, (t + 1) * 64, bufnP + 8192, wave, lane);
    WAIT_VM8(); BAR(); WAIT_LGKM4();
    MFMA_PHASE(0, 0, afrE, b0r);
    // ---- P1 ----
    RD_A(afrO, bc + 16384u);
    stageJ<2>(Ah[0], CDIM, (t + 2) * 64, bufcP + 0, wave, lane);
    WAIT_VM8(); BAR(); WAIT_LGKM8();
    MFMA_PHASE(0, 1, afrE, b1r);
    // ---- P2 ----
    RD_A(afrE, bn + 0u);
    stageJ<2>(Bh[0], CDIM, (t + 2) * 64, bufcP + 16384, wave, lane);
    WAIT_VM8(); BAR(); WAIT_LGKM8();
    MFMA_PHASE(1, 0, afrO, b0r);
    // ---- P3 ----
    RD_B(b0r, bn + 32768u);
    stageJ<2>(Bh[1], CDIM, (t + 2) * 64, bufcP + 24576, wave, lane);
    WAIT_VM8(); BAR();
    MFMA_PHASE(1, 1, afrO, b1r);
  }
  // ---- t = 10: only A1(11) still stages; vm decay 8/6/4/2 ----
  {
    const unsigned bc = 0u, bn = 65536u;
    unsigned short* bufnP = lds + 32768;
    RD_B(b1r, bc + 49152u);
    stageJ<2>(Ah[1], CDIM, 11 * 64, bufnP + 8192, wave, lane);
    WAIT_VM8(); BAR(); WAIT_LGKM4();
    MFMA_PHASE(0, 0, afrE, b0r);

    RD_A(afrO, bc + 16384u);
    WAIT_VM6(); BAR(); WAIT_LGKM8();
    MFMA_PHASE(0, 1, afrE, b1r);

    RD_A(afrE, bn + 0u);
    WAIT_VM4(); BAR(); WAIT_LGKM8();
    MFMA_PHASE(1, 0, afrO, b0r);

    RD_B(b0r, bn + 32768u);
    WAIT_VM2(); BAR();
    MFMA_PHASE(1, 1, afrO, b1r);
  }
  // ---- t = 11: all data in buf1; no stages ----
  {
    const unsigned bc = 65536u;
    RD_B(b1r, bc + 49152u);
    WAIT_VM0(); BAR(); WAIT_LGKM4();
    MFMA_PHASE(0, 0, afrE, b0r);

    RD_A(afrO, bc + 16384u);
    WAIT_LGKM8();
    MFMA_PHASE(0, 1, afrE, b1r);

    WAIT_LGKM0();
    MFMA_PHASE(1, 0, afrO, b0r);
    MFMA_PHASE(1, 1, afrO, b1r);
  }

  // Epilogue: slice-routed writes (last slice transposed to vTd[b][d][n]).
#pragma unroll
  for (int gm = 0; gm < 2; ++gm)
#pragma unroll
    for (int gn = 0; gn < 2; ++gn) {
      const int cb2 = c0 + gn * 128 + wx * 32;
      const int slice = cb2 / 768;
      const int rb = m0 + gm * 128 + wy * 64;
      if (slice == lastSlice) {
#pragma unroll
        for (int mf = 0; mf < 4; ++mf) {
          const int row0 = rb + mf * 16 + quad * 4;
          const int b = row0 >> 10, n0 = row0 & 1023;
#pragma unroll
          for (int nf = 0; nf < 2; ++nf) {
            const int gcol = cb2 + nf * 16 + l16;
            const int d = gcol - slice * 768;
            const float bv = bias[gcol];
            uint2 o;
            o.x = (unsigned)f2bf(acc[gm][gn][mf][nf][0] + bv) |
                  ((unsigned)f2bf(acc[gm][gn][mf][nf][1] + bv) << 16);
            o.y = (unsigned)f2bf(acc[gm][gn][mf][nf][2] + bv) |
                  ((unsigned)f2bf(acc[gm][gn][mf][nf][3] + bv) << 16);
            *(uint2*)&vTd[((size_t)b * CDIM + d) * MDIM + n0] = o;
          }
        }
      } else {
        const size_t sbase = (size_t)slice * ROWS * 768;
#pragma unroll
        for (int mf = 0; mf < 4; ++mf)
#pragma unroll
          for (int nf = 0; nf < 2; ++nf) {
            const int gcol = cb2 + nf * 16 + l16;
            const int lcol = gcol - slice * 768;
            const float bv = bias[gcol];
#pragma unroll
            for (int rg = 0; rg < 4; ++rg) {
              const int row = rb + mf * 16 + quad * 4 + rg;
              Y[sbase + (size_t)row * 768 + lcol] =
                  f2bf(acc[gm][gn][mf][nf][rg] + bv);
            }
          }
      }
    }
}

// ---------------------------------------------------------------------------
// cq projection on the 64x128 engine: flat grid 768 (=3.0 blocks/CU).
// ---------------------------------------------------------------------------
__global__ __launch_bounds__(256, 4) void gemm_proj64(
    const unsigned short* __restrict__ A, const unsigned short* __restrict__ Bt,
    const float* __restrict__ bias, unsigned short* __restrict__ Y) {
  __shared__ __align__(16) unsigned short As[64 * 64];
  __shared__ __align__(16) unsigned short Bs[128 * 64];
  const int lin = blockIdx.x;
  const int xcd = lin & 7, j = lin >> 3;            // j in [0,96)
  const int m0 = (xcd * 16 + (j & 15)) * 64;
  const int c0 = (j >> 4) * 128;
  const int tid = threadIdx.x;
  const int wave = tid >> 6, lane = tid & 63;
  const int wx = wave & 1, wy = wave >> 1;
  const int quad = lane >> 4, l16 = lane & 15;
  const f32x4 vzero = {0.f, 0.f, 0.f, 0.f};
  f32x4 acc[2][4];
#pragma unroll
  for (int mt = 0; mt < 2; ++mt)
#pragma unroll
    for (int nt = 0; nt < 4; ++nt) acc[mt][nt] = vzero;
  mfma_loop64h(A + (size_t)m0 * CDIM, CDIM, Bt + (size_t)c0 * CDIM, CDIM,
               CDIM, As, Bs, acc, wave, lane);
#pragma unroll
  for (int mt = 0; mt < 2; ++mt)
#pragma unroll
    for (int nt = 0; nt < 4; ++nt) {
      const int col = c0 + wx * 64 + nt * 16 + l16;
      const float bv = bias[col];
#pragma unroll
      for (int rg = 0; rg < 4; ++rg) {
        const int row = m0 + wy * 32 + mt * 16 + quad * 4 + rg;
        Y[(size_t)row * 768 + col] = f2bf(acc[mt][nt][rg] + bv);
      }
    }
}

// FFN on the 64x128 engine (f32 out): flat grid 768.
__global__ __launch_bounds__(256, 4) void gemm_ffn64(
    const unsigned short* __restrict__ A, const unsigned short* __restrict__ Bt,
    const float* __restrict__ bias, float* __restrict__ Y) {
  __shared__ __align__(16) unsigned short As[64 * 64];
  __shared__ __align__(16) unsigned short Bs[128 * 64];
  const int lin = blockIdx.x;
  const int xcd = lin & 7, j = lin >> 3;
  const int m0 = (xcd * 16 + (j & 15)) * 64;
  const int c0 = (j >> 4) * 128;
  const int tid = threadIdx.x;
  const int wave = tid >> 6, lane = tid & 63;
  const int wx = wave & 1, wy = wave >> 1;
  const int quad = lane >> 4, l16 = lane & 15;
  const f32x4 vzero = {0.f, 0.f, 0.f, 0.f};
  f32x4 acc[2][4];
#pragma unroll
  for (int mt = 0; mt < 2; ++mt)
#pragma unroll
    for (int nt = 0; nt < 4; ++nt) acc[mt][nt] = vzero;
  mfma_loop64h(A + (size_t)m0 * CDIM, CDIM, Bt + (size_t)c0 * CDIM, CDIM,
               CDIM, As, Bs, acc, wave, lane);
#pragma unroll
  for (int mt = 0; mt < 2; ++mt)
#pragma unroll
    for (int nt = 0; nt < 4; ++nt) {
      const int col = c0 + wx * 64 + nt * 16 + l16;
      const float bv = bias[col];
#pragma unroll
      for (int rg = 0; rg < 4; ++rg) {
        const int row = m0 + wy * 32 + mt * 16 + quad * 4 + rg;
        Y[(size_t)row * 768 + col] = acc[mt][nt][rg] + bv;
      }
    }
}

// ---------------------------------------------------------------------------
// Batched QK^T with fused exp + row-sum on the 64x128 engine.
// grid (8, 16, BDIM) = 1024 blocks. Row sums as race-free partials per
// (cblock, wx): rsp[((cb*2+wx)*8 + b)*1024 + row].
// ---------------------------------------------------------------------------
__global__ __launch_bounds__(256, 4) void gemm_qk64(
    const unsigned short* __restrict__ Qb, const unsigned short* __restrict__ Kb,
    const float* __restrict__ mask, unsigned short* __restrict__ S, float scale,
    float* __restrict__ rsp) {
  __shared__ __align__(16) unsigned short As[64 * 64];
  __shared__ __align__(16) unsigned short Bs[128 * 64];
  const int c0 = blockIdx.x * 128;
  const int m0 = blockIdx.y * 64;
  const int b = blockIdx.z;
  const int tid = threadIdx.x;
  const int wave = tid >> 6, lane = tid & 63;
  const int wx = wave & 1, wy = wave >> 1;
  const int quad = lane >> 4, l16 = lane & 15;

  const f32x4 vzero = {0.f, 0.f, 0.f, 0.f};
  f32x4 acc[2][4];
#pragma unroll
  for (int mt = 0; mt < 2; ++mt)
#pragma unroll
    for (int nt = 0; nt < 4; ++nt) acc[mt][nt] = vzero;

  mfma_loop64h(Qb + ((size_t)b * MDIM + m0) * CDIM, CDIM,
               Kb + ((size_t)b * MDIM + c0) * CDIM, CDIM, CDIM,
               As, Bs, acc, wave, lane);

  const float* maskb = mask + b * MDIM;
  float mrow[2][4], rsum[2][4];
#pragma unroll
  for (int mt = 0; mt < 2; ++mt)
#pragma unroll
    for (int rg = 0; rg < 4; ++rg) {
      mrow[mt][rg] = maskb[m0 + wy * 32 + mt * 16 + quad * 4 + rg];
      rsum[mt][rg] = 0.f;
    }
  unsigned short* Sb = S + (size_t)b * MDIM * MDIM;
#pragma unroll
  for (int nt = 0; nt < 4; ++nt) {
    const int col = c0 + wx * 64 + nt * 16 + l16;
    const float mcol = maskb[col];
#pragma unroll
    for (int mt = 0; mt < 2; ++mt)
#pragma unroll
      for (int rg = 0; rg < 4; ++rg) {
        const int row = m0 + wy * 32 + mt * 16 + quad * 4 + rg;
        const float e = (mrow[mt][rg] * mcol != 0.f)
                            ? __expf(acc[mt][nt][rg] * scale)
                            : 1e-30f;
        Sb[(size_t)row * MDIM + col] = f2bf(e);
        rsum[mt][rg] += e;
      }
  }
  for (int off = 1; off < 16; off <<= 1) {
#pragma unroll
    for (int mt = 0; mt < 2; ++mt)
#pragma unroll
      for (int rg = 0; rg < 4; ++rg)
        rsum[mt][rg] += __shfl_xor(rsum[mt][rg], off, 64);
  }
  if (l16 == 0) {
    float* rs = rsp + ((((size_t)blockIdx.x * 2 + wx) * 8 + b) << 10) +
                m0 + wy * 32;
#pragma unroll
    for (int mt = 0; mt < 2; ++mt)
#pragma unroll
      for (int rg = 0; rg < 4; ++rg)
        rs[mt * 16 + quad * 4 + rg] = rsum[mt][rg];
  }
}

// ---------------------------------------------------------------------------
// O = (unnormalized P) @ V, normalized by 1/rowsum, on the 64x128 engine.
// grid (6, 16, BDIM) = 768 blocks.
// ---------------------------------------------------------------------------
__global__ __launch_bounds__(256, 4) void attn_pv64(
    const unsigned short* __restrict__ P, const unsigned short* __restrict__ vT,
    unsigned short* __restrict__ O, const float* __restrict__ rsp) {
  __shared__ __align__(16) unsigned short As[64 * 64];
  __shared__ __align__(16) unsigned short Bs[128 * 64];
  const int c0 = blockIdx.x * 128;
  const int m0 = blockIdx.y * 64;
  const int b = blockIdx.z;
  const int tid = threadIdx.x;
  const int wave = tid >> 6, lane = tid & 63;
  const int wx = wave & 1, wy = wave >> 1;
  const int quad = lane >> 4, l16 = lane & 15;

  const f32x4 vzero = {0.f, 0.f, 0.f, 0.f};
  f32x4 acc[2][4];
#pragma unroll
  for (int mt = 0; mt < 2; ++mt)
#pragma unroll
    for (int nt = 0; nt < 4; ++nt) acc[mt][nt] = vzero;

  mfma_loop64h(P + ((size_t)b * MDIM + m0) * MDIM, MDIM,
               vT + ((size_t)b * CDIM + c0) * MDIM, MDIM, MDIM,
               As, Bs, acc, wave, lane);

  const float* rsb = rsp + (((size_t)l16 * 8 + b) << 10) + m0 + wy * 32;
  float inv[2][4];
#pragma unroll
  for (int mt = 0; mt < 2; ++mt)
#pragma unroll
    for (int rg = 0; rg < 4; ++rg) {
      float s = rsb[mt * 16 + quad * 4 + rg];
      for (int off = 1; off < 16; off <<= 1) s += __shfl_xor(s, off, 64);
      inv[mt][rg] = 1.f / s;
    }
#pragma unroll
  for (int mt = 0; mt < 2; ++mt)
#pragma unroll
    for (int nt = 0; nt < 4; ++nt)
#pragma unroll
      for (int rg = 0; rg < 4; ++rg) {
        const int row = m0 + wy * 32 + mt * 16 + quad * 4 + rg;
        const int col = c0 + wx * 64 + nt * 16 + l16;
        O[(size_t)(b * MDIM + row) * CDIM + col] =
            f2bf(acc[mt][nt][rg] * inv[mt][rg]);
      }
}

// ---------------------------------------------------------------------------
extern "C" void kernel_launch(void* const* d_in, const int* in_sizes, int n_in,
                              void* d_out, int out_size, void* d_ws, size_t ws_size,
                              hipStream_t stream) {
  const float* layout_x = (const float*)d_in[0];
  const float* text_x   = (const float*)d_in[1];
  const float* maskp    = (const float*)d_in[2];
  const float* Wqkv     = (const float*)d_in[3];
  const float* bqkv     = (const float*)d_in[4];
  const float* Wq       = (const float*)d_in[5];
  const float* bq       = (const float*)d_in[6];
  const float* Wkv      = (const float*)d_in[7];
  const float* bkv      = (const float*)d_in[8];
  const float* Wffn     = (const float*)d_in[9];
  const float* bffn     = (const float*)d_in[10];
  float* out = (float*)d_out;
  char* ws = (char*)d_ws;

  const float scale = 1.0f / sqrtf((float)CDIM);

  // ---- workspace (bytes), live total 87,949,312 ----
  unsigned short* xlb    = (unsigned short*)(ws);              // -> attn1/merge
  unsigned short* xtb    = (unsigned short*)(ws + 12582912);   // dead after proj -> rsp
  unsigned short* Wqkv_t = (unsigned short*)(ws + 25165824);
  unsigned short* Wq_t   = (unsigned short*)(ws + 28704768);
  unsigned short* Wkv_t  = (unsigned short*)(ws + 29884416);
  unsigned short* Wffn_t = (unsigned short*)(ws + 32243712);
  unsigned short* Qb     = (unsigned short*)(ws + 33423360);   // slice1=K contiguous
  unsigned short* Kb     = (unsigned short*)(ws + 46006272);
  unsigned short* vT     = (unsigned short*)(ws + 58589184);   // V^T
  unsigned short* S      = (unsigned short*)(ws + 71172096);   // 16.8 MB
  unsigned short* attn1  = xlb;
  unsigned short* cqb    = Qb;           // Qb dead after qk1
  // cross-attention K / V^T live in d_out (exactly 2 x 12,582,912 B);
  // ffn overwrites out only after pv2 consumed them.
  unsigned short* cK  = (unsigned short*)out;
  unsigned short* cVT = (unsigned short*)out + 6291456;
  // rowsum partials (512 KB) in the xtb region (dead after gemm_qkvkv).
  float* rsp = (float*)xtb;

  // 1) prologue: input converts + weight transposes
  prologue<<<10176, 256, 0, stream>>>(layout_x, text_x, xlb, xtb,
                                      Wqkv, Wq, Wkv, Wffn,
                                      Wqkv_t, Wq_t, Wkv_t, Wffn_t);
  // 2) combined 256^2 engine: {Q,K -> Qb,Kb; V -> vT^T} + {cK -> out; cV -> cVT^T}
  gemm_qkvkv<<<480, 512, 0, stream>>>(xlb, Wqkv_t, bqkv, Qb, vT,
                                      xtb, Wkv_t, bkv, cK, cVT);
  // 3) S = exp(scale*QK^T) masked; rowsum partials
  gemm_qk64<<<dim3(8, 16, BDIM), 256, 0, stream>>>(Qb, Kb, maskp, S, scale, rsp);
  // 4) attn1 = bf16((S @ V) / rowsum)
  attn_pv64<<<dim3(6, 16, BDIM), 256, 0, stream>>>(S, vT, attn1, rsp);
  // 5) cq = attn1@Wq+bq
  gemm_proj64<<<768, 256, 0, stream>>>(attn1, Wq_t, bq, cqb);
  // 6) S = exp(scale*cq cK^T) masked; rowsum partials
  gemm_qk64<<<dim3(8, 16, BDIM), 256, 0, stream>>>(cqb, cK, maskp, S, scale, rsp);
  // 7) merge = bf16((S @ cV) / rowsum)
  attn_pv64<<<dim3(6, 16, BDIM), 256, 0, stream>>>(S, cVT, attn1, rsp);
  // 8) out = merge @ Wffn + bffn (f32)
  gemm_ffn64<<<768, 256, 0, stream>>>(attn1, Wffn_t, bffn, out);
}